// Round 1
// baseline (1259.107 us; speedup 1.0000x reference)
//
#include <hip/hip_runtime.h>
#include <hip/hip_bf16.h>

typedef __bf16 bf16x8 __attribute__((ext_vector_type(8)));
typedef __bf16 bf16x4 __attribute__((ext_vector_type(4)));
typedef float  f32x4  __attribute__((ext_vector_type(4)));

#define QL 1024
#define NH 32
#define NKV 8
#define HD 128
#define KVLEN 2048
#define QKV_LD 6144

// ---------------------------------------------------------------------------
// fp32 -> bf16 plain cast, vectorized (float4 in, 4x bf16 out)
// ---------------------------------------------------------------------------
__global__ __launch_bounds__(256) void cast_plain(const float* __restrict__ in,
                                                  __bf16* __restrict__ out, int n4) {
  int i = blockIdx.x * 256 + threadIdx.x;
  if (i >= n4) return;
  float4 v = ((const float4*)in)[i];
  bf16x4 o;
  o[0] = (__bf16)v.x; o[1] = (__bf16)v.y; o[2] = (__bf16)v.z; o[3] = (__bf16)v.w;
  ((bf16x4*)out)[i] = o;
}

// ---------------------------------------------------------------------------
// fp32 (R x C) -> bf16 (C x R) transpose-cast, 64x64 LDS tiles
// ---------------------------------------------------------------------------
__global__ __launch_bounds__(256) void transpose_cast(const float* __restrict__ in,
                                                      __bf16* __restrict__ out,
                                                      int R, int C) {
  __shared__ __bf16 tile[64][65];
  int r0 = blockIdx.y * 64, c0 = blockIdx.x * 64;
  int t = threadIdx.x;
  int tr = t >> 4, tc = (t & 15) * 4;
#pragma unroll
  for (int pass = 0; pass < 4; pass++) {
    int r = pass * 16 + tr;
    float4 v = *(const float4*)(in + (size_t)(r0 + r) * C + c0 + tc);
    tile[r][tc + 0] = (__bf16)v.x;
    tile[r][tc + 1] = (__bf16)v.y;
    tile[r][tc + 2] = (__bf16)v.z;
    tile[r][tc + 3] = (__bf16)v.w;
  }
  __syncthreads();
#pragma unroll
  for (int pass = 0; pass < 4; pass++) {
    int cc = pass * 16 + tr;   // output row (= original col)
    bf16x4 o;
#pragma unroll
    for (int j = 0; j < 4; j++) o[j] = tile[tc + j][cc];
    *(bf16x4*)(out + (size_t)(c0 + cc) * R + r0 + tc) = o;
  }
}

// ---------------------------------------------------------------------------
// C[M,N] = A[M,K] @ Bt[N,K]^T   (bf16 in, fp32 acc, bf16 or fp32 out)
// 128x128 tile, BK=32, 4 waves (2x2), each wave 64x64 via 4x4 mfma 16x16x32
// ---------------------------------------------------------------------------
template <int OUT_BF16>
__global__ __launch_bounds__(256) void gemm_bt(const __bf16* __restrict__ A,
                                               const __bf16* __restrict__ Bt,
                                               void* __restrict__ Cout,
                                               int M, int N, int K) {
  __shared__ __attribute__((aligned(16))) __bf16 sA[128 * 32];
  __shared__ __attribute__((aligned(16))) __bf16 sB[128 * 32];
  const int tid = threadIdx.x;
  const int lane = tid & 63;
  const int wave = tid >> 6;
  const int wm = wave >> 1, wn = wave & 1;
  const int quad = lane >> 4, l16 = lane & 15;
  const int row0 = blockIdx.y * 128, col0 = blockIdx.x * 128;
  const int sr = tid >> 2, skc = tid & 3;

  const __bf16* Ag0 = A + (size_t)(row0 + sr) * K + skc * 8;
  const __bf16* Ag1 = Ag0 + (size_t)64 * K;
  const __bf16* Bg0 = Bt + (size_t)(col0 + sr) * K + skc * 8;
  const __bf16* Bg1 = Bg0 + (size_t)64 * K;

  f32x4 acc[4][4];
#pragma unroll
  for (int mt = 0; mt < 4; mt++)
#pragma unroll
    for (int nt = 0; nt < 4; nt++) acc[mt][nt] = (f32x4){0.f, 0.f, 0.f, 0.f};

  for (int k0 = 0; k0 < K; k0 += 32) {
    bf16x8 a0 = *(const bf16x8*)(Ag0 + k0);
    bf16x8 a1 = *(const bf16x8*)(Ag1 + k0);
    bf16x8 b0 = *(const bf16x8*)(Bg0 + k0);
    bf16x8 b1 = *(const bf16x8*)(Bg1 + k0);
    __syncthreads();  // previous iter's frag reads complete
    *(bf16x8*)(sA + tid * 8) = a0;
    *(bf16x8*)(sA + 2048 + tid * 8) = a1;
    *(bf16x8*)(sB + tid * 8) = b0;
    *(bf16x8*)(sB + 2048 + tid * 8) = b1;
    __syncthreads();
    bf16x8 af[4], bfr[4];
#pragma unroll
    for (int mt = 0; mt < 4; mt++)
      af[mt] = *(const bf16x8*)(sA + (wm * 64 + mt * 16 + l16) * 32 + quad * 8);
#pragma unroll
    for (int nt = 0; nt < 4; nt++)
      bfr[nt] = *(const bf16x8*)(sB + (wn * 64 + nt * 16 + l16) * 32 + quad * 8);
#pragma unroll
    for (int mt = 0; mt < 4; mt++)
#pragma unroll
      for (int nt = 0; nt < 4; nt++)
        acc[mt][nt] = __builtin_amdgcn_mfma_f32_16x16x32_bf16(af[mt], bfr[nt],
                                                              acc[mt][nt], 0, 0, 0);
  }

  // C/D layout: col = lane&15, row = quad*4 + reg
#pragma unroll
  for (int mt = 0; mt < 4; mt++) {
#pragma unroll
    for (int r = 0; r < 4; r++) {
      int grow = row0 + wm * 64 + mt * 16 + quad * 4 + r;
#pragma unroll
      for (int nt = 0; nt < 4; nt++) {
        int gcol = col0 + wn * 64 + nt * 16 + l16;
        float v = acc[mt][nt][r];
        if (OUT_BF16)
          ((__bf16*)Cout)[(size_t)grow * N + gcol] = (__bf16)v;
        else
          ((float*)Cout)[(size_t)grow * N + gcol] = v;
      }
    }
  }
}

// ---------------------------------------------------------------------------
// RoPE in-place on qkv (q heads 0..31, k heads 32..39). pos = 1024 + (t%1024)
// ---------------------------------------------------------------------------
__global__ __launch_bounds__(256) void rope_kernel(__bf16* __restrict__ qkv) {
  int idx = blockIdx.x * 256 + threadIdx.x;  // 4096 * 40 * 64
  int m = idx & 63;
  int rest = idx >> 6;
  int t = rest / 40;
  int head = rest - t * 40;
  int i = t & (QL - 1);
  float pos = (float)(1024 + i);
  // inv_freq = theta^(-m/64) = 2^(-m * log2(1e6)/64)
  float ang = pos * exp2f(-(float)m * 0.31143075889569403f);
  float c = cosf(ang), sn = sinf(ang);
  size_t base = (size_t)t * QKV_LD + head * HD;
  float x0 = (float)qkv[base + m];
  float x1 = (float)qkv[base + 64 + m];
  qkv[base + m]      = (__bf16)(x0 * c - x1 * sn);
  qkv[base + 64 + m] = (__bf16)(x1 * c + x0 * sn);
}

// ---------------------------------------------------------------------------
// k_all[b][kvh][p][d] <- cache (p<1024, fp32) or roped new k from qkv (p>=1024)
// ---------------------------------------------------------------------------
__global__ __launch_bounds__(256) void kv_build_k(const float* __restrict__ kcache,
                                                  const __bf16* __restrict__ qkv,
                                                  __bf16* __restrict__ k_all) {
  int idx = blockIdx.x * 256 + threadIdx.x;  // 2^20
  int d8 = (idx & 15) * 8;
  int p = (idx >> 4) & (KVLEN - 1);
  int bk = idx >> 15;  // b*8 + kvh
  int b = bk >> 3, kvh = bk & 7;
  __bf16* dst = k_all + ((size_t)bk * KVLEN + p) * HD + d8;
  if (p < 1024) {
    const float* src = kcache + ((size_t)(b * KVLEN + p) * NKV + kvh) * HD + d8;
    bf16x8 o;
#pragma unroll
    for (int j = 0; j < 8; j++) o[j] = (__bf16)src[j];
    *(bf16x8*)dst = o;
  } else {
    const __bf16* src = qkv + (size_t)(b * QL + p - 1024) * QKV_LD + 4096 + kvh * HD + d8;
    *(bf16x8*)dst = *(const bf16x8*)src;
  }
}

// ---------------------------------------------------------------------------
// v_allT[b][kvh][d][p]  (d-major so PV B-fragments are key-contiguous)
// ---------------------------------------------------------------------------
__global__ __launch_bounds__(256) void kv_build_vT(const float* __restrict__ vcache,
                                                   const __bf16* __restrict__ qkv,
                                                   __bf16* __restrict__ v_allT) {
  __shared__ __bf16 tile[64][130];
  int blk = blockIdx.x;  // 32 bk * 32 ptiles
  int pt = blk & 31, bk = blk >> 5;
  int b = bk >> 3, kvh = bk & 7;
  int p0 = pt * 64;
  int t = threadIdx.x;
  int lr = t >> 4, d8 = (t & 15) * 8;
#pragma unroll
  for (int pass = 0; pass < 4; pass++) {
    int pl = pass * 16 + lr;
    int p = p0 + pl;
    if (p < 1024) {
      const float* src = vcache + ((size_t)(b * KVLEN + p) * NKV + kvh) * HD + d8;
#pragma unroll
      for (int j = 0; j < 8; j++) tile[pl][d8 + j] = (__bf16)src[j];
    } else {
      const __bf16* src = qkv + (size_t)(b * QL + p - 1024) * QKV_LD + 5120 + kvh * HD + d8;
      bf16x8 v = *(const bf16x8*)src;
#pragma unroll
      for (int j = 0; j < 8; j++) tile[pl][d8 + j] = v[j];
    }
  }
  __syncthreads();
#pragma unroll
  for (int pass = 0; pass < 4; pass++) {
    int d = (t >> 3) + pass * 32;
    int ps = (t & 7) * 8;
    bf16x8 o;
#pragma unroll
    for (int j = 0; j < 8; j++) o[j] = tile[ps + j][d];
    *(bf16x8*)(v_allT + ((size_t)bk * HD + d) * KVLEN + p0 + ps) = o;
  }
}

// ---------------------------------------------------------------------------
// Flash attention: one wave per (b, h, 16-query tile). GQA kvh = h/4.
// valid keys for local query i: i < k <= i+1024  (exactly 1024 keys)
// ---------------------------------------------------------------------------
__global__ __launch_bounds__(256) void attn_kernel(const __bf16* __restrict__ qkv,
                                                   const __bf16* __restrict__ k_all,
                                                   const __bf16* __restrict__ v_allT,
                                                   __bf16* __restrict__ out) {
  __shared__ __attribute__((aligned(16))) __bf16 sP[4][16 * 48];  // stride 48 avoids bank pathologies
  const int lane = threadIdx.x & 63;
  const int wave = threadIdx.x >> 6;
  const int wid = blockIdx.x * 4 + wave;  // 0..8191
  const int qt = wid & 63;
  const int h = (wid >> 6) & 31;
  const int b = wid >> 11;
  const int kvh = h >> 2;
  const int quad = lane >> 4, l16 = lane & 15;
  const int i0 = qt * 16;

  // Q fragments (A-layout: m = lane&15, k = quad*8+j), head-dim K split in 4x32
  bf16x8 qf[4];
  {
    const __bf16* qb = qkv + (size_t)(b * QL + i0 + l16) * QKV_LD + h * HD + quad * 8;
#pragma unroll
    for (int kc = 0; kc < 4; kc++) qf[kc] = *(const bf16x8*)(qb + kc * 32);
  }
  const __bf16* kb = k_all + (size_t)(b * NKV + kvh) * KVLEN * HD;
  const __bf16* vb = v_allT + (size_t)(b * NKV + kvh) * HD * KVLEN;

  f32x4 o[8];
#pragma unroll
  for (int dt = 0; dt < 8; dt++) o[dt] = (f32x4){0.f, 0.f, 0.f, 0.f};
  float m_i[4] = {-1e30f, -1e30f, -1e30f, -1e30f};
  float l_i[4] = {0.f, 0.f, 0.f, 0.f};
  __bf16* myP = &sP[wave][0];
  const float scale = 0.08838834764831845f;  // 1/sqrt(128)

  const int c0 = (i0 + 1) & ~31;
  const int kend = i0 + 1039;  // max valid key = (i0+15) + 1024; chunks stay < 2048

  for (int c = c0; c <= kend; c += 32) {
    // S = Q @ K^T for 32 keys (two 16-key n-tiles)
    f32x4 s[2];
#pragma unroll
    for (int nt = 0; nt < 2; nt++) {
      s[nt] = (f32x4){0.f, 0.f, 0.f, 0.f};
      const __bf16* kp = kb + (size_t)(c + nt * 16 + l16) * HD + quad * 8;
#pragma unroll
      for (int kc = 0; kc < 4; kc++) {
        bf16x8 kf = *(const bf16x8*)(kp + kc * 32);
        s[nt] = __builtin_amdgcn_mfma_f32_16x16x32_bf16(qf[kc], kf, s[nt], 0, 0, 0);
      }
    }
    // mask + scale; C-layout: row = i0 + quad*4 + r, col(key) = c + nt*16 + l16
    float sv[2][4], rmax[4];
#pragma unroll
    for (int r = 0; r < 4; r++) {
      int irow = i0 + quad * 4 + r;
      float mx = -1e30f;
#pragma unroll
      for (int nt = 0; nt < 2; nt++) {
        int kk = c + nt * 16 + l16;
        bool valid = (kk > irow) && (kk <= irow + 1024);
        float v = valid ? s[nt][r] * scale : -1e30f;
        sv[nt][r] = v;
        mx = fmaxf(mx, v);
      }
      rmax[r] = mx;
    }
#pragma unroll
    for (int d = 1; d < 16; d <<= 1)
#pragma unroll
      for (int r = 0; r < 4; r++) rmax[r] = fmaxf(rmax[r], __shfl_xor(rmax[r], d, 64));

    float alpha[4], rsum[4];
#pragma unroll
    for (int r = 0; r < 4; r++) {
      float mn = fmaxf(m_i[r], rmax[r]);
      alpha[r] = __expf(m_i[r] - mn);
      m_i[r] = mn;
      float p0 = __expf(sv[0][r] - mn);
      float p1 = __expf(sv[1][r] - mn);
      myP[(quad * 4 + r) * 48 + l16]      = (__bf16)p0;  // P[qrow][key]
      myP[(quad * 4 + r) * 48 + 16 + l16] = (__bf16)p1;
      rsum[r] = p0 + p1;
    }
#pragma unroll
    for (int d = 1; d < 16; d <<= 1)
#pragma unroll
      for (int r = 0; r < 4; r++) rsum[r] += __shfl_xor(rsum[r], d, 64);
#pragma unroll
    for (int r = 0; r < 4; r++) l_i[r] = l_i[r] * alpha[r] + rsum[r];

    asm volatile("s_waitcnt lgkmcnt(0)" ::: "memory");  // P writes -> reads (wave-internal)
    bf16x8 pf = *(const bf16x8*)(myP + l16 * 48 + quad * 8);  // A-layout: P[m=l16][k=quad*8+j]
#pragma unroll
    for (int dt = 0; dt < 8; dt++)
#pragma unroll
      for (int r = 0; r < 4; r++) o[dt][r] *= alpha[r];
#pragma unroll
    for (int dt = 0; dt < 8; dt++) {
      bf16x8 vf = *(const bf16x8*)(vb + (size_t)(dt * 16 + l16) * KVLEN + c + quad * 8);
      o[dt] = __builtin_amdgcn_mfma_f32_16x16x32_bf16(pf, vf, o[dt], 0, 0, 0);
    }
  }

  float inv[4];
#pragma unroll
  for (int r = 0; r < 4; r++) inv[r] = 1.0f / l_i[r];
#pragma unroll
  for (int dt = 0; dt < 8; dt++)
#pragma unroll
    for (int r = 0; r < 4; r++)
      out[(size_t)(b * QL + i0 + quad * 4 + r) * (NH * HD) + h * HD + dt * 16 + l16] =
          (__bf16)(o[dt][r] * inv[r]);
}

// ---------------------------------------------------------------------------
extern "C" void kernel_launch(void* const* d_in, const int* in_sizes, int n_in,
                              void* d_out, int out_size, void* d_ws, size_t ws_size,
                              hipStream_t stream) {
  const float* hidden = (const float*)d_in[0];
  const float* wq = (const float*)d_in[1];
  const float* wk = (const float*)d_in[2];
  const float* wv = (const float*)d_in[3];
  const float* wo = (const float*)d_in[4];
  const float* kcache = (const float*)d_in[5];
  const float* vcache = (const float*)d_in[6];
  (void)in_sizes; (void)n_in; (void)out_size; (void)ws_size;

  // ws layout (160 MB total, with two safe aliases):
  //   [0,   33.5M)  hidden_bf16   -> later reused as attn_out_bf16
  //   [33.5M, 83.9M) wqkvT_bf16   -> later reused as woT_bf16
  //   [83.9M, 134.2M) qkv_bf16 (T x 6144: q|k|v)
  //   [134.2M, 151M)  k_all  [b][kvh][p][d]
  //   [151M,  167.8M) v_allT [b][kvh][d][p]
  char* w = (char*)d_ws;
  __bf16* hid_b  = (__bf16*)(w);
  __bf16* wqkvT  = (__bf16*)(w + 33554432ULL);
  __bf16* qkv    = (__bf16*)(w + 83886080ULL);
  __bf16* k_all  = (__bf16*)(w + 134217728ULL);
  __bf16* v_allT = (__bf16*)(w + 150994944ULL);
  __bf16* attn   = hid_b;   // hidden dead after QKV GEMM
  __bf16* woT    = wqkvT;   // wqkvT dead after QKV GEMM

  cast_plain<<<16384, 256, 0, stream>>>(hidden, hid_b, 4194304);
  transpose_cast<<<dim3(64, 64), 256, 0, stream>>>(wq, wqkvT, 4096, 4096);
  transpose_cast<<<dim3(16, 64), 256, 0, stream>>>(wk, wqkvT + 16777216ULL, 4096, 1024);
  transpose_cast<<<dim3(16, 64), 256, 0, stream>>>(wv, wqkvT + 20971520ULL, 4096, 1024);
  gemm_bt<1><<<dim3(48, 32), 256, 0, stream>>>(hid_b, wqkvT, (void*)qkv, 4096, 6144, 4096);
  rope_kernel<<<40960, 256, 0, stream>>>(qkv);
  kv_build_k<<<4096, 256, 0, stream>>>(kcache, qkv, k_all);
  kv_build_vT<<<1024, 256, 0, stream>>>(vcache, qkv, v_allT);
  attn_kernel<<<2048, 256, 0, stream>>>(qkv, k_all, v_allT, attn);
  transpose_cast<<<dim3(64, 64), 256, 0, stream>>>(wo, woT, 4096, 4096);
  gemm_bt<0><<<dim3(32, 32), 256, 0, stream>>>(attn, woT, d_out, 4096, 4096, 4096);
}

// Round 2
// 1037.616 us; speedup vs baseline: 1.2135x; 1.2135x over previous
//
#include <hip/hip_runtime.h>
#include <hip/hip_bf16.h>

typedef __bf16 bf16x8 __attribute__((ext_vector_type(8)));
typedef __bf16 bf16x4 __attribute__((ext_vector_type(4)));
typedef float  f32x4  __attribute__((ext_vector_type(4)));

#define QL 1024
#define NH 32
#define NKV 8
#define HD 128
#define KVLEN 2048
#define QKV_LD 6144

// async global->LDS, 16B per lane. LDS dest semantics: wave-uniform base + lane*16,
// we pass per-lane ptr = base + lane*16 so both interpretations agree.
typedef const __attribute__((address_space(1))) void gv_t;
typedef __attribute__((address_space(3))) void lv_t;
__device__ __forceinline__ void gll16(const void* g, void* l) {
  __builtin_amdgcn_global_load_lds((gv_t*)g, (lv_t*)l, 16, 0, 0);
}

// ---------------------------------------------------------------------------
// fp32 -> bf16 plain cast
// ---------------------------------------------------------------------------
__global__ __launch_bounds__(256) void cast_plain(const float* __restrict__ in,
                                                  __bf16* __restrict__ out, int n4) {
  int i = blockIdx.x * 256 + threadIdx.x;
  if (i >= n4) return;
  float4 v = ((const float4*)in)[i];
  bf16x4 o;
  o[0] = (__bf16)v.x; o[1] = (__bf16)v.y; o[2] = (__bf16)v.z; o[3] = (__bf16)v.w;
  ((bf16x4*)out)[i] = o;
}

// ---------------------------------------------------------------------------
// fp32 (R x C) -> bf16 (C x R) transpose-cast
// ---------------------------------------------------------------------------
__global__ __launch_bounds__(256) void transpose_cast(const float* __restrict__ in,
                                                      __bf16* __restrict__ out,
                                                      int R, int C) {
  __shared__ __bf16 tile[64][65];
  int r0 = blockIdx.y * 64, c0 = blockIdx.x * 64;
  int t = threadIdx.x;
  int tr = t >> 4, tc = (t & 15) * 4;
#pragma unroll
  for (int pass = 0; pass < 4; pass++) {
    int r = pass * 16 + tr;
    float4 v = *(const float4*)(in + (size_t)(r0 + r) * C + c0 + tc);
    tile[r][tc + 0] = (__bf16)v.x;
    tile[r][tc + 1] = (__bf16)v.y;
    tile[r][tc + 2] = (__bf16)v.z;
    tile[r][tc + 3] = (__bf16)v.w;
  }
  __syncthreads();
#pragma unroll
  for (int pass = 0; pass < 4; pass++) {
    int cc = pass * 16 + tr;
    bf16x4 o;
#pragma unroll
    for (int j = 0; j < 4; j++) o[j] = tile[tc + j][cc];
    *(bf16x4*)(out + (size_t)(c0 + cc) * R + r0 + tc) = o;
  }
}

// ---------------------------------------------------------------------------
// C[M,N] = A[M,K] @ Bt[N,K]^T, m97 structure: global_load_lds width=16 staging
// 128x128 tile, BK=32, 4 waves (2x2), each wave 64x64 via 4x4 mfma 16x16x32
// ---------------------------------------------------------------------------
template <int OUT_BF16>
__global__ __launch_bounds__(256) void gemm_bt(const __bf16* __restrict__ A,
                                               const __bf16* __restrict__ Bt,
                                               void* __restrict__ Cout,
                                               int M, int N, int K) {
  __shared__ __attribute__((aligned(16))) __bf16 sA[128 * 32];
  __shared__ __attribute__((aligned(16))) __bf16 sB[128 * 32];
  const int tid = threadIdx.x;
  const int lane = tid & 63;
  const int wave = tid >> 6;
  const int wm = wave >> 1, wn = wave & 1;
  const int quad = lane >> 4, l16 = lane & 15;
  const int row0 = blockIdx.y * 128, col0 = blockIdx.x * 128;

  // 16B chunk index: c = wave*128 + lane (call 0), +64 (call 1); chunk c -> row c>>2, k16 (c&3)*8
  const int c1 = wave * 128 + lane;
  const int r1 = c1 >> 2, kq = (c1 & 3) * 8;
  const __bf16* gA0 = A + (size_t)(row0 + r1) * K + kq;
  const __bf16* gA1 = gA0 + (size_t)16 * K;
  const __bf16* gB0 = Bt + (size_t)(col0 + r1) * K + kq;
  const __bf16* gB1 = gB0 + (size_t)16 * K;
  __bf16* lA0 = sA + c1 * 8;
  __bf16* lA1 = sA + c1 * 8 + 512;
  __bf16* lB0 = sB + c1 * 8;
  __bf16* lB1 = sB + c1 * 8 + 512;

  f32x4 acc[4][4];
#pragma unroll
  for (int mt = 0; mt < 4; mt++)
#pragma unroll
    for (int nt = 0; nt < 4; nt++) acc[mt][nt] = (f32x4){0.f, 0.f, 0.f, 0.f};

  for (int k0 = 0; k0 < K; k0 += 32) {
    __syncthreads();  // previous iter's frag reads complete
    gll16(gA0 + k0, lA0);
    gll16(gA1 + k0, lA1);
    gll16(gB0 + k0, lB0);
    gll16(gB1 + k0, lB1);
    __syncthreads();  // compiler drains vmcnt before barrier
    bf16x8 af[4], bfr[4];
#pragma unroll
    for (int mt = 0; mt < 4; mt++)
      af[mt] = *(const bf16x8*)(sA + (wm * 64 + mt * 16 + l16) * 32 + quad * 8);
#pragma unroll
    for (int nt = 0; nt < 4; nt++)
      bfr[nt] = *(const bf16x8*)(sB + (wn * 64 + nt * 16 + l16) * 32 + quad * 8);
#pragma unroll
    for (int mt = 0; mt < 4; mt++)
#pragma unroll
      for (int nt = 0; nt < 4; nt++)
        acc[mt][nt] = __builtin_amdgcn_mfma_f32_16x16x32_bf16(af[mt], bfr[nt],
                                                              acc[mt][nt], 0, 0, 0);
  }

  // C/D layout: col = lane&15, row = quad*4 + reg
#pragma unroll
  for (int mt = 0; mt < 4; mt++) {
#pragma unroll
    for (int r = 0; r < 4; r++) {
      int grow = row0 + wm * 64 + mt * 16 + quad * 4 + r;
#pragma unroll
      for (int nt = 0; nt < 4; nt++) {
        int gcol = col0 + wn * 64 + nt * 16 + l16;
        float v = acc[mt][nt][r];
        if (OUT_BF16)
          ((__bf16*)Cout)[(size_t)grow * N + gcol] = (__bf16)v;
        else
          ((float*)Cout)[(size_t)grow * N + gcol] = v;
      }
    }
  }
}

// ---------------------------------------------------------------------------
// RoPE in-place on qkv (q heads 0..31, k heads 32..39). pos = 1024 + (t%1024)
// ---------------------------------------------------------------------------
__global__ __launch_bounds__(256) void rope_kernel(__bf16* __restrict__ qkv) {
  int idx = blockIdx.x * 256 + threadIdx.x;
  int m = idx & 63;
  int rest = idx >> 6;
  int t = rest / 40;
  int head = rest - t * 40;
  int i = t & (QL - 1);
  float pos = (float)(1024 + i);
  float ang = pos * exp2f(-(float)m * 0.31143075889569403f);
  float c = cosf(ang), sn = sinf(ang);
  size_t base = (size_t)t * QKV_LD + head * HD;
  float x0 = (float)qkv[base + m];
  float x1 = (float)qkv[base + 64 + m];
  qkv[base + m]      = (__bf16)(x0 * c - x1 * sn);
  qkv[base + 64 + m] = (__bf16)(x1 * c + x0 * sn);
}

// ---------------------------------------------------------------------------
// k_all[b][kvh][p][d] <- cache (p<1024) or roped new k from qkv (p>=1024)
// ---------------------------------------------------------------------------
__global__ __launch_bounds__(256) void kv_build_k(const float* __restrict__ kcache,
                                                  const __bf16* __restrict__ qkv,
                                                  __bf16* __restrict__ k_all) {
  int idx = blockIdx.x * 256 + threadIdx.x;
  int d8 = (idx & 15) * 8;
  int p = (idx >> 4) & (KVLEN - 1);
  int bk = idx >> 15;
  int b = bk >> 3, kvh = bk & 7;
  __bf16* dst = k_all + ((size_t)bk * KVLEN + p) * HD + d8;
  if (p < 1024) {
    const float* src = kcache + ((size_t)(b * KVLEN + p) * NKV + kvh) * HD + d8;
    bf16x8 o;
#pragma unroll
    for (int j = 0; j < 8; j++) o[j] = (__bf16)src[j];
    *(bf16x8*)dst = o;
  } else {
    const __bf16* src = qkv + (size_t)(b * QL + p - 1024) * QKV_LD + 4096 + kvh * HD + d8;
    *(bf16x8*)dst = *(const bf16x8*)src;
  }
}

// ---------------------------------------------------------------------------
// v_allT[b][kvh][d][p]
// ---------------------------------------------------------------------------
__global__ __launch_bounds__(256) void kv_build_vT(const float* __restrict__ vcache,
                                                   const __bf16* __restrict__ qkv,
                                                   __bf16* __restrict__ v_allT) {
  __shared__ __bf16 tile[64][130];
  int blk = blockIdx.x;
  int pt = blk & 31, bk = blk >> 5;
  int b = bk >> 3, kvh = bk & 7;
  int p0 = pt * 64;
  int t = threadIdx.x;
  int lr = t >> 4, d8 = (t & 15) * 8;
#pragma unroll
  for (int pass = 0; pass < 4; pass++) {
    int pl = pass * 16 + lr;
    int p = p0 + pl;
    if (p < 1024) {
      const float* src = vcache + ((size_t)(b * KVLEN + p) * NKV + kvh) * HD + d8;
#pragma unroll
      for (int j = 0; j < 8; j++) tile[pl][d8 + j] = (__bf16)src[j];
    } else {
      const __bf16* src = qkv + (size_t)(b * QL + p - 1024) * QKV_LD + 5120 + kvh * HD + d8;
      bf16x8 v = *(const bf16x8*)src;
#pragma unroll
      for (int j = 0; j < 8; j++) tile[pl][d8 + j] = v[j];
    }
  }
  __syncthreads();
#pragma unroll
  for (int pass = 0; pass < 4; pass++) {
    int d = (t >> 3) + pass * 32;
    int ps = (t & 7) * 8;
    bf16x8 o;
#pragma unroll
    for (int j = 0; j < 8; j++) o[j] = tile[ps + j][d];
    *(bf16x8*)(v_allT + ((size_t)bk * HD + d) * KVLEN + p0 + ps) = o;
  }
}

// ---------------------------------------------------------------------------
// Flash attention v2: block = (b, kvh, 32-query tile), wave = one of 4 GQA heads.
// 64-key chunks; no-max-subtraction softmax (scores bounded << 88); row-sum l
// via MFMA with all-ones B fragment; interior chunks skip masking.
// Key->lane map: key = c + 4*l16 + nt  => P stores are 4 contiguous bf16 (b64).
// P rows padded to 72 bf16 => A-frag ds_read_b128 conflict-free (9*l16 mod 32).
// ---------------------------------------------------------------------------
__global__ __launch_bounds__(256) void attn_kernel(const __bf16* __restrict__ qkv,
                                                   const __bf16* __restrict__ k_all,
                                                   const __bf16* __restrict__ v_allT,
                                                   __bf16* __restrict__ out) {
  __shared__ __attribute__((aligned(16))) __bf16 sP[4][32 * 72];
  const int lane = threadIdx.x & 63;
  const int wave = threadIdx.x >> 6;
  const int quad = lane >> 4, l16 = lane & 15;
  const int blk = blockIdx.x;          // qt(32) | kvh(8) | b(4)
  const int qt = blk & 31;
  const int kvh = (blk >> 5) & 7;
  const int b = blk >> 8;
  const int h = kvh * 4 + wave;
  const int i0 = qt * 32;

  // Q fragments (A-layout: m=l16, k=quad*8+j), 2 m-tiles x 4 k-chunks
  bf16x8 qf[2][4];
#pragma unroll
  for (int mt = 0; mt < 2; mt++) {
    const __bf16* qb = qkv + (size_t)(b * QL + i0 + mt * 16 + l16) * QKV_LD + h * HD + quad * 8;
#pragma unroll
    for (int kc = 0; kc < 4; kc++) qf[mt][kc] = *(const bf16x8*)(qb + kc * 32);
  }
  const __bf16* kb = k_all + (size_t)(b * NKV + kvh) * KVLEN * HD;
  const __bf16* vb = v_allT + (size_t)(b * NKV + kvh) * HD * KVLEN;

  f32x4 o[8][2];
#pragma unroll
  for (int dt = 0; dt < 8; dt++)
#pragma unroll
    for (int mt = 0; mt < 2; mt++) o[dt][mt] = (f32x4){0.f, 0.f, 0.f, 0.f};
  f32x4 lac[2];
  lac[0] = (f32x4){0.f, 0.f, 0.f, 0.f};
  lac[1] = (f32x4){0.f, 0.f, 0.f, 0.f};

  bf16x8 ones;
#pragma unroll
  for (int j = 0; j < 8; j++) ones[j] = (__bf16)1.0f;

  __bf16* myP = &sP[wave][0];
  const float ES = 0.12751744f;  // (1/sqrt(128)) * log2(e): exp(s*scale) = exp2(s*ES)

  const int cs = (i0 + 1) & ~63;  // 17 chunks of 64 keys cover [i0+1, i0+1055]

  for (int ci = 0; ci < 17; ci++) {
    const int c = cs + ci * 64;
    // ---- S = Q @ K^T, keys c + 4*l16 + nt
    f32x4 s[2][4];
#pragma unroll
    for (int nt = 0; nt < 4; nt++) {
      s[0][nt] = (f32x4){0.f, 0.f, 0.f, 0.f};
      s[1][nt] = (f32x4){0.f, 0.f, 0.f, 0.f};
      const __bf16* kp = kb + (size_t)(c + 4 * l16 + nt) * HD + quad * 8;
#pragma unroll
      for (int kc = 0; kc < 4; kc++) {
        bf16x8 kf = *(const bf16x8*)(kp + kc * 32);
        s[0][nt] = __builtin_amdgcn_mfma_f32_16x16x32_bf16(qf[0][kc], kf, s[0][nt], 0, 0, 0);
        s[1][nt] = __builtin_amdgcn_mfma_f32_16x16x32_bf16(qf[1][kc], kf, s[1][nt], 0, 0, 0);
      }
    }
    // ---- P = exp(S*scale), masked only on boundary chunks; store to LDS
    const bool full = (c >= i0 + 32) && (c <= i0 + 961);
#pragma unroll
    for (int mt = 0; mt < 2; mt++) {
#pragma unroll
      for (int r = 0; r < 4; r++) {
        bf16x4 pk;
        if (full) {
#pragma unroll
          for (int nt = 0; nt < 4; nt++) pk[nt] = (__bf16)exp2f(s[mt][nt][r] * ES);
        } else {
          const int irow = i0 + mt * 16 + quad * 4 + r;
#pragma unroll
          for (int nt = 0; nt < 4; nt++) {
            const int kk = c + 4 * l16 + nt;
            const bool valid = (kk > irow) && (kk <= irow + 1024);
            pk[nt] = valid ? (__bf16)exp2f(s[mt][nt][r] * ES) : (__bf16)0.0f;
          }
        }
        *(bf16x4*)(myP + (mt * 16 + quad * 4 + r) * 72 + 4 * l16) = pk;
      }
    }
    asm volatile("s_waitcnt lgkmcnt(0)" ::: "memory");  // P writes -> reads (wave-internal)
    // ---- O += P @ V ; l += P @ ones
#pragma unroll
    for (int kc = 0; kc < 2; kc++) {
      bf16x8 pf0 = *(const bf16x8*)(myP + (l16) * 72 + kc * 32 + quad * 8);
      bf16x8 pf1 = *(const bf16x8*)(myP + (16 + l16) * 72 + kc * 32 + quad * 8);
      lac[0] = __builtin_amdgcn_mfma_f32_16x16x32_bf16(pf0, ones, lac[0], 0, 0, 0);
      lac[1] = __builtin_amdgcn_mfma_f32_16x16x32_bf16(pf1, ones, lac[1], 0, 0, 0);
#pragma unroll
      for (int dt = 0; dt < 8; dt++) {
        bf16x8 vf = *(const bf16x8*)(vb + (size_t)(dt * 16 + l16) * KVLEN + c + kc * 32 + quad * 8);
        o[dt][0] = __builtin_amdgcn_mfma_f32_16x16x32_bf16(pf0, vf, o[dt][0], 0, 0, 0);
        o[dt][1] = __builtin_amdgcn_mfma_f32_16x16x32_bf16(pf1, vf, o[dt][1], 0, 0, 0);
      }
    }
  }

  // ---- epilogue: out = O / l   (every lane holds l for its own rows)
  float inv[2][4];
#pragma unroll
  for (int mt = 0; mt < 2; mt++)
#pragma unroll
    for (int r = 0; r < 4; r++) inv[mt][r] = 1.0f / lac[mt][r];
#pragma unroll
  for (int dt = 0; dt < 8; dt++)
#pragma unroll
    for (int mt = 0; mt < 2; mt++)
#pragma unroll
      for (int r = 0; r < 4; r++)
        out[(size_t)(b * QL + i0 + mt * 16 + quad * 4 + r) * (NH * HD) + h * HD + dt * 16 + l16] =
            (__bf16)(o[dt][mt][r] * inv[mt][r]);
}

// ---------------------------------------------------------------------------
extern "C" void kernel_launch(void* const* d_in, const int* in_sizes, int n_in,
                              void* d_out, int out_size, void* d_ws, size_t ws_size,
                              hipStream_t stream) {
  const float* hidden = (const float*)d_in[0];
  const float* wq = (const float*)d_in[1];
  const float* wk = (const float*)d_in[2];
  const float* wv = (const float*)d_in[3];
  const float* wo = (const float*)d_in[4];
  const float* kcache = (const float*)d_in[5];
  const float* vcache = (const float*)d_in[6];
  (void)in_sizes; (void)n_in; (void)out_size; (void)ws_size;

  char* w = (char*)d_ws;
  __bf16* hid_b  = (__bf16*)(w);
  __bf16* wqkvT  = (__bf16*)(w + 33554432ULL);
  __bf16* qkv    = (__bf16*)(w + 83886080ULL);
  __bf16* k_all  = (__bf16*)(w + 134217728ULL);
  __bf16* v_allT = (__bf16*)(w + 150994944ULL);
  __bf16* attn   = hid_b;   // hidden dead after QKV GEMM
  __bf16* woT    = wqkvT;   // wqkvT dead after QKV GEMM

  cast_plain<<<16384, 256, 0, stream>>>(hidden, hid_b, 4194304);
  transpose_cast<<<dim3(64, 64), 256, 0, stream>>>(wq, wqkvT, 4096, 4096);
  transpose_cast<<<dim3(16, 64), 256, 0, stream>>>(wk, wqkvT + 16777216ULL, 4096, 1024);
  transpose_cast<<<dim3(16, 64), 256, 0, stream>>>(wv, wqkvT + 20971520ULL, 4096, 1024);
  gemm_bt<1><<<dim3(48, 32), 256, 0, stream>>>(hid_b, wqkvT, (void*)qkv, 4096, 6144, 4096);
  rope_kernel<<<40960, 256, 0, stream>>>(qkv);
  kv_build_k<<<4096, 256, 0, stream>>>(kcache, qkv, k_all);
  kv_build_vT<<<1024, 256, 0, stream>>>(vcache, qkv, v_allT);
  attn_kernel<<<1024, 256, 0, stream>>>(qkv, k_all, v_allT, attn);
  transpose_cast<<<dim3(64, 64), 256, 0, stream>>>(wo, woT, 4096, 4096);
  gemm_bt<0><<<dim3(32, 32), 256, 0, stream>>>(attn, woT, d_out, 4096, 4096, 4096);
}

// Round 3
// 864.357 us; speedup vs baseline: 1.4567x; 1.2004x over previous
//
#include <hip/hip_runtime.h>
#include <hip/hip_bf16.h>

typedef __bf16 bf16x8 __attribute__((ext_vector_type(8)));
typedef __bf16 bf16x4 __attribute__((ext_vector_type(4)));
typedef float  f32x4  __attribute__((ext_vector_type(4)));

#define QL 1024
#define NH 32
#define NKV 8
#define HD 128
#define KVLEN 2048
#define QKV_LD 6144

// async global->LDS, 16B per lane. LDS dest = wave-uniform base + lane*16;
// we pass per-lane ptr = base + lane*16 so both interpretations agree.
// Global side addressing is per-lane (gather is allowed on the global side).
typedef const __attribute__((address_space(1))) void gv_t;
typedef __attribute__((address_space(3))) void lv_t;
__device__ __forceinline__ void gll16(const void* g, void* l) {
  __builtin_amdgcn_global_load_lds((gv_t*)g, (lv_t*)l, 16, 0, 0);
}

// ---------------------------------------------------------------------------
// fp32 -> bf16 plain cast
// ---------------------------------------------------------------------------
__global__ __launch_bounds__(256) void cast_plain(const float* __restrict__ in,
                                                  __bf16* __restrict__ out, int n4) {
  int i = blockIdx.x * 256 + threadIdx.x;
  if (i >= n4) return;
  float4 v = ((const float4*)in)[i];
  bf16x4 o;
  o[0] = (__bf16)v.x; o[1] = (__bf16)v.y; o[2] = (__bf16)v.z; o[3] = (__bf16)v.w;
  ((bf16x4*)out)[i] = o;
}

// ---------------------------------------------------------------------------
// fp32 (R x C) -> bf16 (C x R) transpose-cast
// ---------------------------------------------------------------------------
__global__ __launch_bounds__(256) void transpose_cast(const float* __restrict__ in,
                                                      __bf16* __restrict__ out,
                                                      int R, int C) {
  __shared__ __bf16 tile[64][65];
  int r0 = blockIdx.y * 64, c0 = blockIdx.x * 64;
  int t = threadIdx.x;
  int tr = t >> 4, tc = (t & 15) * 4;
#pragma unroll
  for (int pass = 0; pass < 4; pass++) {
    int r = pass * 16 + tr;
    float4 v = *(const float4*)(in + (size_t)(r0 + r) * C + c0 + tc);
    tile[r][tc + 0] = (__bf16)v.x;
    tile[r][tc + 1] = (__bf16)v.y;
    tile[r][tc + 2] = (__bf16)v.z;
    tile[r][tc + 3] = (__bf16)v.w;
  }
  __syncthreads();
#pragma unroll
  for (int pass = 0; pass < 4; pass++) {
    int cc = pass * 16 + tr;
    bf16x4 o;
#pragma unroll
    for (int j = 0; j < 4; j++) o[j] = tile[tc + j][cc];
    *(bf16x4*)(out + (size_t)(c0 + cc) * R + r0 + tc) = o;
  }
}

// ---------------------------------------------------------------------------
// C[M,N] = A[M,K] @ Bt[N,K]^T, m97 structure (global_load_lds width=16)
// ---------------------------------------------------------------------------
template <int OUT_BF16>
__global__ __launch_bounds__(256) void gemm_bt(const __bf16* __restrict__ A,
                                               const __bf16* __restrict__ Bt,
                                               void* __restrict__ Cout,
                                               int M, int N, int K) {
  __shared__ __attribute__((aligned(16))) __bf16 sA[128 * 32];
  __shared__ __attribute__((aligned(16))) __bf16 sB[128 * 32];
  const int tid = threadIdx.x;
  const int lane = tid & 63;
  const int wave = tid >> 6;
  const int wm = wave >> 1, wn = wave & 1;
  const int quad = lane >> 4, l16 = lane & 15;
  const int row0 = blockIdx.y * 128, col0 = blockIdx.x * 128;

  const int c1 = wave * 128 + lane;
  const int r1 = c1 >> 2, kq = (c1 & 3) * 8;
  const __bf16* gA0 = A + (size_t)(row0 + r1) * K + kq;
  const __bf16* gA1 = gA0 + (size_t)16 * K;
  const __bf16* gB0 = Bt + (size_t)(col0 + r1) * K + kq;
  const __bf16* gB1 = gB0 + (size_t)16 * K;
  __bf16* lA0 = sA + c1 * 8;
  __bf16* lA1 = sA + c1 * 8 + 512;
  __bf16* lB0 = sB + c1 * 8;
  __bf16* lB1 = sB + c1 * 8 + 512;

  f32x4 acc[4][4];
#pragma unroll
  for (int mt = 0; mt < 4; mt++)
#pragma unroll
    for (int nt = 0; nt < 4; nt++) acc[mt][nt] = (f32x4){0.f, 0.f, 0.f, 0.f};

  for (int k0 = 0; k0 < K; k0 += 32) {
    __syncthreads();
    gll16(gA0 + k0, lA0);
    gll16(gA1 + k0, lA1);
    gll16(gB0 + k0, lB0);
    gll16(gB1 + k0, lB1);
    __syncthreads();
    bf16x8 af[4], bfr[4];
#pragma unroll
    for (int mt = 0; mt < 4; mt++)
      af[mt] = *(const bf16x8*)(sA + (wm * 64 + mt * 16 + l16) * 32 + quad * 8);
#pragma unroll
    for (int nt = 0; nt < 4; nt++)
      bfr[nt] = *(const bf16x8*)(sB + (wn * 64 + nt * 16 + l16) * 32 + quad * 8);
#pragma unroll
    for (int mt = 0; mt < 4; mt++)
#pragma unroll
      for (int nt = 0; nt < 4; nt++)
        acc[mt][nt] = __builtin_amdgcn_mfma_f32_16x16x32_bf16(af[mt], bfr[nt],
                                                              acc[mt][nt], 0, 0, 0);
  }

#pragma unroll
  for (int mt = 0; mt < 4; mt++) {
#pragma unroll
    for (int r = 0; r < 4; r++) {
      int grow = row0 + wm * 64 + mt * 16 + quad * 4 + r;
#pragma unroll
      for (int nt = 0; nt < 4; nt++) {
        int gcol = col0 + wn * 64 + nt * 16 + l16;
        float v = acc[mt][nt][r];
        if (OUT_BF16)
          ((__bf16*)Cout)[(size_t)grow * N + gcol] = (__bf16)v;
        else
          ((float*)Cout)[(size_t)grow * N + gcol] = v;
      }
    }
  }
}

// ---------------------------------------------------------------------------
// RoPE in-place on qkv
// ---------------------------------------------------------------------------
__global__ __launch_bounds__(256) void rope_kernel(__bf16* __restrict__ qkv) {
  int idx = blockIdx.x * 256 + threadIdx.x;
  int m = idx & 63;
  int rest = idx >> 6;
  int t = rest / 40;
  int head = rest - t * 40;
  int i = t & (QL - 1);
  float pos = (float)(1024 + i);
  float ang = pos * exp2f(-(float)m * 0.31143075889569403f);
  float c = cosf(ang), sn = sinf(ang);
  size_t base = (size_t)t * QKV_LD + head * HD;
  float x0 = (float)qkv[base + m];
  float x1 = (float)qkv[base + 64 + m];
  qkv[base + m]      = (__bf16)(x0 * c - x1 * sn);
  qkv[base + 64 + m] = (__bf16)(x1 * c + x0 * sn);
}

// ---------------------------------------------------------------------------
// k_all[b][kvh][p][d]
// ---------------------------------------------------------------------------
__global__ __launch_bounds__(256) void kv_build_k(const float* __restrict__ kcache,
                                                  const __bf16* __restrict__ qkv,
                                                  __bf16* __restrict__ k_all) {
  int idx = blockIdx.x * 256 + threadIdx.x;
  int d8 = (idx & 15) * 8;
  int p = (idx >> 4) & (KVLEN - 1);
  int bk = idx >> 15;
  int b = bk >> 3, kvh = bk & 7;
  __bf16* dst = k_all + ((size_t)bk * KVLEN + p) * HD + d8;
  if (p < 1024) {
    const float* src = kcache + ((size_t)(b * KVLEN + p) * NKV + kvh) * HD + d8;
    bf16x8 o;
#pragma unroll
    for (int j = 0; j < 8; j++) o[j] = (__bf16)src[j];
    *(bf16x8*)dst = o;
  } else {
    const __bf16* src = qkv + (size_t)(b * QL + p - 1024) * QKV_LD + 4096 + kvh * HD + d8;
    *(bf16x8*)dst = *(const bf16x8*)src;
  }
}

// ---------------------------------------------------------------------------
// v_allT[b][kvh][d][p]
// ---------------------------------------------------------------------------
__global__ __launch_bounds__(256) void kv_build_vT(const float* __restrict__ vcache,
                                                   const __bf16* __restrict__ qkv,
                                                   __bf16* __restrict__ v_allT) {
  __shared__ __bf16 tile[64][130];
  int blk = blockIdx.x;
  int pt = blk & 31, bk = blk >> 5;
  int b = bk >> 3, kvh = bk & 7;
  int p0 = pt * 64;
  int t = threadIdx.x;
  int lr = t >> 4, d8 = (t & 15) * 8;
#pragma unroll
  for (int pass = 0; pass < 4; pass++) {
    int pl = pass * 16 + lr;
    int p = p0 + pl;
    if (p < 1024) {
      const float* src = vcache + ((size_t)(b * KVLEN + p) * NKV + kvh) * HD + d8;
#pragma unroll
      for (int j = 0; j < 8; j++) tile[pl][d8 + j] = (__bf16)src[j];
    } else {
      const __bf16* src = qkv + (size_t)(b * QL + p - 1024) * QKV_LD + 5120 + kvh * HD + d8;
      bf16x8 v = *(const bf16x8*)src;
#pragma unroll
      for (int j = 0; j < 8; j++) tile[pl][d8 + j] = v[j];
    }
  }
  __syncthreads();
#pragma unroll
  for (int pass = 0; pass < 4; pass++) {
    int d = (t >> 3) + pass * 32;
    int ps = (t & 7) * 8;
    bf16x8 o;
#pragma unroll
    for (int j = 0; j < 8; j++) o[j] = tile[ps + j][d];
    *(bf16x8*)(v_allT + ((size_t)bk * HD + d) * KVLEN + p0 + ps) = o;
  }
}

// ---------------------------------------------------------------------------
// Flash attention v3: K/V chunks staged ONCE per block in LDS (4 GQA waves
// share them), async gll16 prefetch pipelined across chunks, XOR-swizzled
// LDS slots for conflict-free ds_read_b128 fragments.
// Block = (qt<<5)|(kvh<<2)|b: qt in high bits => all 32 q-tiles of one
// (b,kvh) land on the same XCD (L2-resident 1MB K+V working set).
// ---------------------------------------------------------------------------
__global__ __launch_bounds__(256) void attn_kernel(const __bf16* __restrict__ qkv,
                                                   const __bf16* __restrict__ k_all,
                                                   const __bf16* __restrict__ v_allT,
                                                   __bf16* __restrict__ out) {
  __shared__ __attribute__((aligned(16))) __bf16 sK[64 * 128];   // [key][d], slot-swizzled
  __shared__ __attribute__((aligned(16))) __bf16 sV[128 * 64];   // [d][key], slot-swizzled
  __shared__ __attribute__((aligned(16))) __bf16 sP[4][32 * 72];
  const int tid = threadIdx.x;
  const int lane = tid & 63;
  const int wave = tid >> 6;
  const int quad = lane >> 4, l16 = lane & 15;
  const int bid = blockIdx.x;
  const int b = bid & 3;
  const int kvh = (bid >> 2) & 7;
  const int qt = bid >> 5;
  const int h = kvh * 4 + wave;
  const int i0 = qt * 32;

  const __bf16* kb = k_all + (size_t)(b * NKV + kvh) * KVLEN * HD;
  const __bf16* vb = v_allT + (size_t)(b * NKV + kvh) * HD * KVLEN;

  // Q fragments (A-layout: m=l16, k=quad*8+j), 2 m-tiles x 4 k-chunks
  bf16x8 qf[2][4];
#pragma unroll
  for (int mt = 0; mt < 2; mt++) {
    const __bf16* qb = qkv + (size_t)(b * QL + i0 + mt * 16 + l16) * QKV_LD + h * HD + quad * 8;
#pragma unroll
    for (int kc = 0; kc < 4; kc++) qf[mt][kc] = *(const bf16x8*)(qb + kc * 32);
  }

  // staging address precompute (per j=0..3):
  // K unit: g=wave*4+j; local key = g*4+quad; slot = l16 ^ (g&7)  (16 slots/row)
  // V unit: g=wave*4+j; d = g*8+(lane>>3); slot = (lane&7)^((lane>>3)&7) (8 slots/row)
  int kgo[4], vgo[4];
#pragma unroll
  for (int j = 0; j < 4; j++) {
    int g = wave * 4 + j;
    kgo[j] = (g * 4 + quad) * HD + (l16 ^ (g & 7)) * 8;
    int d = g * 8 + (lane >> 3);
    vgo[j] = d * KVLEN + ((lane & 7) ^ ((lane >> 3) & 7)) * 8;
  }
  __bf16* kls = sK + (wave * 4) * 512 + lane * 8;  // +j*512
  __bf16* vls = sV + (wave * 4) * 512 + lane * 8;

  f32x4 o[8][2];
#pragma unroll
  for (int dt = 0; dt < 8; dt++)
#pragma unroll
    for (int mt = 0; mt < 2; mt++) o[dt][mt] = (f32x4){0.f, 0.f, 0.f, 0.f};
  f32x4 lac[2];
  lac[0] = (f32x4){0.f, 0.f, 0.f, 0.f};
  lac[1] = (f32x4){0.f, 0.f, 0.f, 0.f};

  bf16x8 ones;
#pragma unroll
  for (int j = 0; j < 8; j++) ones[j] = (__bf16)1.0f;

  __bf16* myP = &sP[wave][0];
  const float ES = 0.12751744f;  // (1/sqrt(128)) * log2(e)

  const int cs = (i0 + 1) & ~63;  // 17 chunks of 64 cover the 1024-key window
  const int xsw = l16 & 7;        // read-side slot swizzle

  // preload chunk 0
#pragma unroll
  for (int j = 0; j < 4; j++) gll16(kb + (size_t)cs * HD + kgo[j], kls + j * 512);
#pragma unroll
  for (int j = 0; j < 4; j++) gll16(vb + (size_t)cs + vgo[j], vls + j * 512);

  for (int ci = 0; ci < 17; ci++) {
    const int c = cs + ci * 64;
    __syncthreads();  // A: vmcnt drained -> chunk ci staged; sV safe from prev iter
    // ---- S = Q @ K^T, keys c + 4*l16 + nt, from swizzled sK
    f32x4 s[2][4];
#pragma unroll
    for (int nt = 0; nt < 4; nt++) {
      s[0][nt] = (f32x4){0.f, 0.f, 0.f, 0.f};
      s[1][nt] = (f32x4){0.f, 0.f, 0.f, 0.f};
      const __bf16* kp = sK + (4 * l16 + nt) * HD;
#pragma unroll
      for (int kc = 0; kc < 4; kc++) {
        bf16x8 kf = *(const bf16x8*)(kp + ((4 * kc + quad) ^ xsw) * 8);
        s[0][nt] = __builtin_amdgcn_mfma_f32_16x16x32_bf16(qf[0][kc], kf, s[0][nt], 0, 0, 0);
        s[1][nt] = __builtin_amdgcn_mfma_f32_16x16x32_bf16(qf[1][kc], kf, s[1][nt], 0, 0, 0);
      }
    }
    __syncthreads();  // B: all waves done reading sK
    if (ci < 16) {    // prefetch K(ci+1): overlaps exp + PV below
#pragma unroll
      for (int j = 0; j < 4; j++) gll16(kb + (size_t)(c + 64) * HD + kgo[j], kls + j * 512);
    }
    // ---- P = exp(S*scale) -> LDS (wave-local slice)
    const bool full = (c >= i0 + 32) && (c <= i0 + 961);
#pragma unroll
    for (int mt = 0; mt < 2; mt++) {
#pragma unroll
      for (int r = 0; r < 4; r++) {
        bf16x4 pk;
        if (full) {
#pragma unroll
          for (int nt = 0; nt < 4; nt++) pk[nt] = (__bf16)exp2f(s[mt][nt][r] * ES);
        } else {
          const int irow = i0 + mt * 16 + quad * 4 + r;
#pragma unroll
          for (int nt = 0; nt < 4; nt++) {
            const int kk = c + 4 * l16 + nt;
            const bool valid = (kk > irow) && (kk <= irow + 1024);
            pk[nt] = valid ? (__bf16)exp2f(s[mt][nt][r] * ES) : (__bf16)0.0f;
          }
        }
        *(bf16x4*)(myP + (mt * 16 + quad * 4 + r) * 72 + 4 * l16) = pk;
      }
    }
    asm volatile("s_waitcnt lgkmcnt(0)" ::: "memory");  // P writes -> reads (wave-internal)
    // ---- O += P @ V ; l += P @ ones   (V from swizzled sV)
#pragma unroll
    for (int kc = 0; kc < 2; kc++) {
      bf16x8 pf0 = *(const bf16x8*)(myP + (l16) * 72 + kc * 32 + quad * 8);
      bf16x8 pf1 = *(const bf16x8*)(myP + (16 + l16) * 72 + kc * 32 + quad * 8);
      lac[0] = __builtin_amdgcn_mfma_f32_16x16x32_bf16(pf0, ones, lac[0], 0, 0, 0);
      lac[1] = __builtin_amdgcn_mfma_f32_16x16x32_bf16(pf1, ones, lac[1], 0, 0, 0);
#pragma unroll
      for (int dt = 0; dt < 8; dt++) {
        bf16x8 vf = *(const bf16x8*)(sV + (dt * 16 + l16) * 64 + ((kc * 4 + quad) ^ xsw) * 8);
        o[dt][0] = __builtin_amdgcn_mfma_f32_16x16x32_bf16(pf0, vf, o[dt][0], 0, 0, 0);
        o[dt][1] = __builtin_amdgcn_mfma_f32_16x16x32_bf16(pf1, vf, o[dt][1], 0, 0, 0);
      }
    }
    __syncthreads();  // C: all waves done reading sV
    if (ci < 16) {    // prefetch V(ci+1)
#pragma unroll
      for (int j = 0; j < 4; j++) gll16(vb + (size_t)(c + 64) + vgo[j], vls + j * 512);
    }
  }

  // ---- epilogue: out = O / l
  float inv[2][4];
#pragma unroll
  for (int mt = 0; mt < 2; mt++)
#pragma unroll
    for (int r = 0; r < 4; r++) inv[mt][r] = 1.0f / lac[mt][r];
#pragma unroll
  for (int dt = 0; dt < 8; dt++)
#pragma unroll
    for (int mt = 0; mt < 2; mt++)
#pragma unroll
      for (int r = 0; r < 4; r++)
        out[(size_t)(b * QL + i0 + mt * 16 + quad * 4 + r) * (NH * HD) + h * HD + dt * 16 + l16] =
            (__bf16)(o[dt][mt][r] * inv[mt][r]);
}

// ---------------------------------------------------------------------------
extern "C" void kernel_launch(void* const* d_in, const int* in_sizes, int n_in,
                              void* d_out, int out_size, void* d_ws, size_t ws_size,
                              hipStream_t stream) {
  const float* hidden = (const float*)d_in[0];
  const float* wq = (const float*)d_in[1];
  const float* wk = (const float*)d_in[2];
  const float* wv = (const float*)d_in[3];
  const float* wo = (const float*)d_in[4];
  const float* kcache = (const float*)d_in[5];
  const float* vcache = (const float*)d_in[6];
  (void)in_sizes; (void)n_in; (void)out_size; (void)ws_size;

  char* w = (char*)d_ws;
  __bf16* hid_b  = (__bf16*)(w);
  __bf16* wqkvT  = (__bf16*)(w + 33554432ULL);
  __bf16* qkv    = (__bf16*)(w + 83886080ULL);
  __bf16* k_all  = (__bf16*)(w + 134217728ULL);
  __bf16* v_allT = (__bf16*)(w + 150994944ULL);
  __bf16* attn   = hid_b;   // hidden dead after QKV GEMM
  __bf16* woT    = wqkvT;   // wqkvT dead after QKV GEMM

  cast_plain<<<16384, 256, 0, stream>>>(hidden, hid_b, 4194304);
  transpose_cast<<<dim3(64, 64), 256, 0, stream>>>(wq, wqkvT, 4096, 4096);
  transpose_cast<<<dim3(16, 64), 256, 0, stream>>>(wk, wqkvT + 16777216ULL, 4096, 1024);
  transpose_cast<<<dim3(16, 64), 256, 0, stream>>>(wv, wqkvT + 20971520ULL, 4096, 1024);
  gemm_bt<1><<<dim3(48, 32), 256, 0, stream>>>(hid_b, wqkvT, (void*)qkv, 4096, 6144, 4096);
  rope_kernel<<<40960, 256, 0, stream>>>(qkv);
  kv_build_k<<<4096, 256, 0, stream>>>(kcache, qkv, k_all);
  kv_build_vT<<<1024, 256, 0, stream>>>(vcache, qkv, v_allT);
  attn_kernel<<<1024, 256, 0, stream>>>(qkv, k_all, v_allT, attn);
  transpose_cast<<<dim3(64, 64), 256, 0, stream>>>(wo, woT, 4096, 4096);
  gemm_bt<0><<<dim3(32, 32), 256, 0, stream>>>(attn, woT, d_out, 4096, 4096, 4096);
}

// Round 4
// 838.407 us; speedup vs baseline: 1.5018x; 1.0310x over previous
//
#include <hip/hip_runtime.h>
#include <hip/hip_bf16.h>

typedef __bf16 bf16x8 __attribute__((ext_vector_type(8)));
typedef __bf16 bf16x4 __attribute__((ext_vector_type(4)));
typedef float  f32x4  __attribute__((ext_vector_type(4)));

#define QL 1024
#define NH 32
#define NKV 8
#define HD 128
#define KVLEN 2048
#define QKV_LD 6144

// async global->LDS, 16B per lane. LDS dest = wave-uniform base + lane*16;
// we pass per-lane ptr = base + lane*16 so both interpretations agree.
// Global side addressing is per-lane (gather is allowed on the global side).
typedef const __attribute__((address_space(1))) void gv_t;
typedef __attribute__((address_space(3))) void lv_t;
__device__ __forceinline__ void gll16(const void* g, void* l) {
  __builtin_amdgcn_global_load_lds((gv_t*)g, (lv_t*)l, 16, 0, 0);
}

// ---------------------------------------------------------------------------
// fp32 -> bf16 plain cast
// ---------------------------------------------------------------------------
__global__ __launch_bounds__(256) void cast_plain(const float* __restrict__ in,
                                                  __bf16* __restrict__ out, int n4) {
  int i = blockIdx.x * 256 + threadIdx.x;
  if (i >= n4) return;
  float4 v = ((const float4*)in)[i];
  bf16x4 o;
  o[0] = (__bf16)v.x; o[1] = (__bf16)v.y; o[2] = (__bf16)v.z; o[3] = (__bf16)v.w;
  ((bf16x4*)out)[i] = o;
}

// ---------------------------------------------------------------------------
// fp32 (R x C) -> bf16 (C x R) transpose-cast
// ---------------------------------------------------------------------------
__global__ __launch_bounds__(256) void transpose_cast(const float* __restrict__ in,
                                                      __bf16* __restrict__ out,
                                                      int R, int C) {
  __shared__ __bf16 tile[64][65];
  int r0 = blockIdx.y * 64, c0 = blockIdx.x * 64;
  int t = threadIdx.x;
  int tr = t >> 4, tc = (t & 15) * 4;
#pragma unroll
  for (int pass = 0; pass < 4; pass++) {
    int r = pass * 16 + tr;
    float4 v = *(const float4*)(in + (size_t)(r0 + r) * C + c0 + tc);
    tile[r][tc + 0] = (__bf16)v.x;
    tile[r][tc + 1] = (__bf16)v.y;
    tile[r][tc + 2] = (__bf16)v.z;
    tile[r][tc + 3] = (__bf16)v.w;
  }
  __syncthreads();
#pragma unroll
  for (int pass = 0; pass < 4; pass++) {
    int cc = pass * 16 + tr;
    bf16x4 o;
#pragma unroll
    for (int j = 0; j < 4; j++) o[j] = tile[tc + j][cc];
    *(bf16x4*)(out + (size_t)(c0 + cc) * R + r0 + tc) = o;
  }
}

// ---------------------------------------------------------------------------
// C[M,N] = A[M,K] @ Bt[N,K]^T, m97 structure (global_load_lds width=16)
// + XOR-swizzled LDS layout: physical slot s of row r holds logical k-quad
//   q = s ^ ((r>>1)&3). Swizzle applied on the GLOBAL side of gll16 (free),
//   making fragment ds_read_b128 conflict-free (was 8-way, 2.5e7 conflicts).
// ---------------------------------------------------------------------------
template <int OUT_BF16>
__global__ __launch_bounds__(256) void gemm_bt(const __bf16* __restrict__ A,
                                               const __bf16* __restrict__ Bt,
                                               void* __restrict__ Cout,
                                               int M, int N, int K) {
  __shared__ __attribute__((aligned(16))) __bf16 sA[128 * 32];
  __shared__ __attribute__((aligned(16))) __bf16 sB[128 * 32];
  const int tid = threadIdx.x;
  const int lane = tid & 63;
  const int wave = tid >> 6;
  const int wm = wave >> 1, wn = wave & 1;
  const int quad = lane >> 4, l16 = lane & 15;
  const int row0 = blockIdx.y * 128, col0 = blockIdx.x * 128;

  // store-side: thread tid fills physical 16B slot tid of region j;
  // row = j*64 + (tid>>2), slot-in-row s = tid&3, logical quad fetched:
  // q = s ^ ((row>>1)&3) = (tid&3) ^ ((tid>>3)&3)
  const int rloc = tid >> 2;
  const int qsel = (tid & 3) ^ ((tid >> 3) & 3);
  const __bf16* gA0 = A + (size_t)(row0 + rloc) * K + qsel * 8;
  const __bf16* gA1 = A + (size_t)(row0 + 64 + rloc) * K + qsel * 8;
  const __bf16* gB0 = Bt + (size_t)(col0 + rloc) * K + qsel * 8;
  const __bf16* gB1 = Bt + (size_t)(col0 + 64 + rloc) * K + qsel * 8;
  __bf16* lA0 = sA + tid * 8;
  __bf16* lA1 = sA + 2048 + tid * 8;
  __bf16* lB0 = sB + tid * 8;
  __bf16* lB1 = sB + 2048 + tid * 8;

  // read-side swizzle: row = ..*16 + l16 => ((row>>1)&3) = (l16>>1)&3
  const int xsw = (l16 >> 1) & 3;

  f32x4 acc[4][4];
#pragma unroll
  for (int mt = 0; mt < 4; mt++)
#pragma unroll
    for (int nt = 0; nt < 4; nt++) acc[mt][nt] = (f32x4){0.f, 0.f, 0.f, 0.f};

  for (int k0 = 0; k0 < K; k0 += 32) {
    __syncthreads();
    gll16(gA0 + k0, lA0);
    gll16(gA1 + k0, lA1);
    gll16(gB0 + k0, lB0);
    gll16(gB1 + k0, lB1);
    __syncthreads();
    bf16x8 af[4], bfr[4];
#pragma unroll
    for (int mt = 0; mt < 4; mt++)
      af[mt] = *(const bf16x8*)(sA + (wm * 64 + mt * 16 + l16) * 32 + (quad ^ xsw) * 8);
#pragma unroll
    for (int nt = 0; nt < 4; nt++)
      bfr[nt] = *(const bf16x8*)(sB + (wn * 64 + nt * 16 + l16) * 32 + (quad ^ xsw) * 8);
#pragma unroll
    for (int mt = 0; mt < 4; mt++)
#pragma unroll
      for (int nt = 0; nt < 4; nt++)
        acc[mt][nt] = __builtin_amdgcn_mfma_f32_16x16x32_bf16(af[mt], bfr[nt],
                                                              acc[mt][nt], 0, 0, 0);
  }

#pragma unroll
  for (int mt = 0; mt < 4; mt++) {
#pragma unroll
    for (int r = 0; r < 4; r++) {
      int grow = row0 + wm * 64 + mt * 16 + quad * 4 + r;
#pragma unroll
      for (int nt = 0; nt < 4; nt++) {
        int gcol = col0 + wn * 64 + nt * 16 + l16;
        float v = acc[mt][nt][r];
        if (OUT_BF16)
          ((__bf16*)Cout)[(size_t)grow * N + gcol] = (__bf16)v;
        else
          ((float*)Cout)[(size_t)grow * N + gcol] = v;
      }
    }
  }
}

// ---------------------------------------------------------------------------
// RoPE in-place on qkv
// ---------------------------------------------------------------------------
__global__ __launch_bounds__(256) void rope_kernel(__bf16* __restrict__ qkv) {
  int idx = blockIdx.x * 256 + threadIdx.x;
  int m = idx & 63;
  int rest = idx >> 6;
  int t = rest / 40;
  int head = rest - t * 40;
  int i = t & (QL - 1);
  float pos = (float)(1024 + i);
  float ang = pos * exp2f(-(float)m * 0.31143075889569403f);
  float c = cosf(ang), sn = sinf(ang);
  size_t base = (size_t)t * QKV_LD + head * HD;
  float x0 = (float)qkv[base + m];
  float x1 = (float)qkv[base + 64 + m];
  qkv[base + m]      = (__bf16)(x0 * c - x1 * sn);
  qkv[base + 64 + m] = (__bf16)(x1 * c + x0 * sn);
}

// ---------------------------------------------------------------------------
// k_all[b][kvh][p][d]
// ---------------------------------------------------------------------------
__global__ __launch_bounds__(256) void kv_build_k(const float* __restrict__ kcache,
                                                  const __bf16* __restrict__ qkv,
                                                  __bf16* __restrict__ k_all) {
  int idx = blockIdx.x * 256 + threadIdx.x;
  int d8 = (idx & 15) * 8;
  int p = (idx >> 4) & (KVLEN - 1);
  int bk = idx >> 15;
  int b = bk >> 3, kvh = bk & 7;
  __bf16* dst = k_all + ((size_t)bk * KVLEN + p) * HD + d8;
  if (p < 1024) {
    const float* src = kcache + ((size_t)(b * KVLEN + p) * NKV + kvh) * HD + d8;
    bf16x8 o;
#pragma unroll
    for (int j = 0; j < 8; j++) o[j] = (__bf16)src[j];
    *(bf16x8*)dst = o;
  } else {
    const __bf16* src = qkv + (size_t)(b * QL + p - 1024) * QKV_LD + 4096 + kvh * HD + d8;
    *(bf16x8*)dst = *(const bf16x8*)src;
  }
}

// ---------------------------------------------------------------------------
// v_allT[b][kvh][d][p]
// ---------------------------------------------------------------------------
__global__ __launch_bounds__(256) void kv_build_vT(const float* __restrict__ vcache,
                                                   const __bf16* __restrict__ qkv,
                                                   __bf16* __restrict__ v_allT) {
  __shared__ __bf16 tile[64][130];
  int blk = blockIdx.x;
  int pt = blk & 31, bk = blk >> 5;
  int b = bk >> 3, kvh = bk & 7;
  int p0 = pt * 64;
  int t = threadIdx.x;
  int lr = t >> 4, d8 = (t & 15) * 8;
#pragma unroll
  for (int pass = 0; pass < 4; pass++) {
    int pl = pass * 16 + lr;
    int p = p0 + pl;
    if (p < 1024) {
      const float* src = vcache + ((size_t)(b * KVLEN + p) * NKV + kvh) * HD + d8;
#pragma unroll
      for (int j = 0; j < 8; j++) tile[pl][d8 + j] = (__bf16)src[j];
    } else {
      const __bf16* src = qkv + (size_t)(b * QL + p - 1024) * QKV_LD + 5120 + kvh * HD + d8;
      bf16x8 v = *(const bf16x8*)src;
#pragma unroll
      for (int j = 0; j < 8; j++) tile[pl][d8 + j] = v[j];
    }
  }
  __syncthreads();
#pragma unroll
  for (int pass = 0; pass < 4; pass++) {
    int d = (t >> 3) + pass * 32;
    int ps = (t & 7) * 8;
    bf16x8 o;
#pragma unroll
    for (int j = 0; j < 8; j++) o[j] = tile[ps + j][d];
    *(bf16x8*)(v_allT + ((size_t)bk * HD + d) * KVLEN + p0 + ps) = o;
  }
}

// ---------------------------------------------------------------------------
// Flash attention v3: K/V staged once per block in LDS, shared by 4 GQA waves,
// async gll16 prefetch pipelined across chunks, XOR-swizzled LDS slots.
// ---------------------------------------------------------------------------
__global__ __launch_bounds__(256) void attn_kernel(const __bf16* __restrict__ qkv,
                                                   const __bf16* __restrict__ k_all,
                                                   const __bf16* __restrict__ v_allT,
                                                   __bf16* __restrict__ out) {
  __shared__ __attribute__((aligned(16))) __bf16 sK[64 * 128];   // [key][d], slot-swizzled
  __shared__ __attribute__((aligned(16))) __bf16 sV[128 * 64];   // [d][key], slot-swizzled
  __shared__ __attribute__((aligned(16))) __bf16 sP[4][32 * 72];
  const int tid = threadIdx.x;
  const int lane = tid & 63;
  const int wave = tid >> 6;
  const int quad = lane >> 4, l16 = lane & 15;
  const int bid = blockIdx.x;
  const int b = bid & 3;
  const int kvh = (bid >> 2) & 7;
  const int qt = bid >> 5;
  const int h = kvh * 4 + wave;
  const int i0 = qt * 32;

  const __bf16* kb = k_all + (size_t)(b * NKV + kvh) * KVLEN * HD;
  const __bf16* vb = v_allT + (size_t)(b * NKV + kvh) * HD * KVLEN;

  bf16x8 qf[2][4];
#pragma unroll
  for (int mt = 0; mt < 2; mt++) {
    const __bf16* qb = qkv + (size_t)(b * QL + i0 + mt * 16 + l16) * QKV_LD + h * HD + quad * 8;
#pragma unroll
    for (int kc = 0; kc < 4; kc++) qf[mt][kc] = *(const bf16x8*)(qb + kc * 32);
  }

  int kgo[4], vgo[4];
#pragma unroll
  for (int j = 0; j < 4; j++) {
    int g = wave * 4 + j;
    kgo[j] = (g * 4 + quad) * HD + (l16 ^ (g & 7)) * 8;
    int d = g * 8 + (lane >> 3);
    vgo[j] = d * KVLEN + ((lane & 7) ^ ((lane >> 3) & 7)) * 8;
  }
  __bf16* kls = sK + (wave * 4) * 512 + lane * 8;  // +j*512
  __bf16* vls = sV + (wave * 4) * 512 + lane * 8;

  f32x4 o[8][2];
#pragma unroll
  for (int dt = 0; dt < 8; dt++)
#pragma unroll
    for (int mt = 0; mt < 2; mt++) o[dt][mt] = (f32x4){0.f, 0.f, 0.f, 0.f};
  f32x4 lac[2];
  lac[0] = (f32x4){0.f, 0.f, 0.f, 0.f};
  lac[1] = (f32x4){0.f, 0.f, 0.f, 0.f};

  bf16x8 ones;
#pragma unroll
  for (int j = 0; j < 8; j++) ones[j] = (__bf16)1.0f;

  __bf16* myP = &sP[wave][0];
  const float ES = 0.12751744f;  // (1/sqrt(128)) * log2(e)

  const int cs = (i0 + 1) & ~63;
  const int xsw = l16 & 7;

#pragma unroll
  for (int j = 0; j < 4; j++) gll16(kb + (size_t)cs * HD + kgo[j], kls + j * 512);
#pragma unroll
  for (int j = 0; j < 4; j++) gll16(vb + (size_t)cs + vgo[j], vls + j * 512);

  for (int ci = 0; ci < 17; ci++) {
    const int c = cs + ci * 64;
    __syncthreads();  // A: chunk ci staged; sV safe from prev iter
    f32x4 s[2][4];
#pragma unroll
    for (int nt = 0; nt < 4; nt++) {
      s[0][nt] = (f32x4){0.f, 0.f, 0.f, 0.f};
      s[1][nt] = (f32x4){0.f, 0.f, 0.f, 0.f};
      const __bf16* kp = sK + (4 * l16 + nt) * HD;
#pragma unroll
      for (int kc = 0; kc < 4; kc++) {
        bf16x8 kf = *(const bf16x8*)(kp + ((4 * kc + quad) ^ xsw) * 8);
        s[0][nt] = __builtin_amdgcn_mfma_f32_16x16x32_bf16(qf[0][kc], kf, s[0][nt], 0, 0, 0);
        s[1][nt] = __builtin_amdgcn_mfma_f32_16x16x32_bf16(qf[1][kc], kf, s[1][nt], 0, 0, 0);
      }
    }
    __syncthreads();  // B: all waves done reading sK
    if (ci < 16) {
#pragma unroll
      for (int j = 0; j < 4; j++) gll16(kb + (size_t)(c + 64) * HD + kgo[j], kls + j * 512);
    }
    const bool full = (c >= i0 + 32) && (c <= i0 + 961);
#pragma unroll
    for (int mt = 0; mt < 2; mt++) {
#pragma unroll
      for (int r = 0; r < 4; r++) {
        bf16x4 pk;
        if (full) {
#pragma unroll
          for (int nt = 0; nt < 4; nt++) pk[nt] = (__bf16)exp2f(s[mt][nt][r] * ES);
        } else {
          const int irow = i0 + mt * 16 + quad * 4 + r;
#pragma unroll
          for (int nt = 0; nt < 4; nt++) {
            const int kk = c + 4 * l16 + nt;
            const bool valid = (kk > irow) && (kk <= irow + 1024);
            pk[nt] = valid ? (__bf16)exp2f(s[mt][nt][r] * ES) : (__bf16)0.0f;
          }
        }
        *(bf16x4*)(myP + (mt * 16 + quad * 4 + r) * 72 + 4 * l16) = pk;
      }
    }
    asm volatile("s_waitcnt lgkmcnt(0)" ::: "memory");
#pragma unroll
    for (int kc = 0; kc < 2; kc++) {
      bf16x8 pf0 = *(const bf16x8*)(myP + (l16) * 72 + kc * 32 + quad * 8);
      bf16x8 pf1 = *(const bf16x8*)(myP + (16 + l16) * 72 + kc * 32 + quad * 8);
      lac[0] = __builtin_amdgcn_mfma_f32_16x16x32_bf16(pf0, ones, lac[0], 0, 0, 0);
      lac[1] = __builtin_amdgcn_mfma_f32_16x16x32_bf16(pf1, ones, lac[1], 0, 0, 0);
#pragma unroll
      for (int dt = 0; dt < 8; dt++) {
        bf16x8 vf = *(const bf16x8*)(sV + (dt * 16 + l16) * 64 + ((kc * 4 + quad) ^ xsw) * 8);
        o[dt][0] = __builtin_amdgcn_mfma_f32_16x16x32_bf16(pf0, vf, o[dt][0], 0, 0, 0);
        o[dt][1] = __builtin_amdgcn_mfma_f32_16x16x32_bf16(pf1, vf, o[dt][1], 0, 0, 0);
      }
    }
    __syncthreads();  // C: all waves done reading sV
    if (ci < 16) {
#pragma unroll
      for (int j = 0; j < 4; j++) gll16(vb + (size_t)(c + 64) + vgo[j], vls + j * 512);
    }
  }

  float inv[2][4];
#pragma unroll
  for (int mt = 0; mt < 2; mt++)
#pragma unroll
    for (int r = 0; r < 4; r++) inv[mt][r] = 1.0f / lac[mt][r];
#pragma unroll
  for (int dt = 0; dt < 8; dt++)
#pragma unroll
    for (int mt = 0; mt < 2; mt++)
#pragma unroll
      for (int r = 0; r < 4; r++)
        out[(size_t)(b * QL + i0 + mt * 16 + quad * 4 + r) * (NH * HD) + h * HD + dt * 16 + l16] =
            (__bf16)(o[dt][mt][r] * inv[mt][r]);
}

// ---------------------------------------------------------------------------
extern "C" void kernel_launch(void* const* d_in, const int* in_sizes, int n_in,
                              void* d_out, int out_size, void* d_ws, size_t ws_size,
                              hipStream_t stream) {
  const float* hidden = (const float*)d_in[0];
  const float* wq = (const float*)d_in[1];
  const float* wk = (const float*)d_in[2];
  const float* wv = (const float*)d_in[3];
  const float* wo = (const float*)d_in[4];
  const float* kcache = (const float*)d_in[5];
  const float* vcache = (const float*)d_in[6];
  (void)in_sizes; (void)n_in; (void)out_size; (void)ws_size;

  char* w = (char*)d_ws;
  __bf16* hid_b  = (__bf16*)(w);
  __bf16* wqkvT  = (__bf16*)(w + 33554432ULL);
  __bf16* qkv    = (__bf16*)(w + 83886080ULL);
  __bf16* k_all  = (__bf16*)(w + 134217728ULL);
  __bf16* v_allT = (__bf16*)(w + 150994944ULL);
  __bf16* attn   = hid_b;   // hidden dead after QKV GEMM
  __bf16* woT    = wqkvT;   // wqkvT dead after QKV GEMM

  cast_plain<<<16384, 256, 0, stream>>>(hidden, hid_b, 4194304);
  transpose_cast<<<dim3(64, 64), 256, 0, stream>>>(wq, wqkvT, 4096, 4096);
  transpose_cast<<<dim3(16, 64), 256, 0, stream>>>(wk, wqkvT + 16777216ULL, 4096, 1024);
  transpose_cast<<<dim3(16, 64), 256, 0, stream>>>(wv, wqkvT + 20971520ULL, 4096, 1024);
  gemm_bt<1><<<dim3(48, 32), 256, 0, stream>>>(hid_b, wqkvT, (void*)qkv, 4096, 6144, 4096);
  rope_kernel<<<40960, 256, 0, stream>>>(qkv);
  kv_build_k<<<4096, 256, 0, stream>>>(kcache, qkv, k_all);
  kv_build_vT<<<1024, 256, 0, stream>>>(vcache, qkv, v_allT);
  attn_kernel<<<1024, 256, 0, stream>>>(qkv, k_all, v_allT, attn);
  transpose_cast<<<dim3(64, 64), 256, 0, stream>>>(wo, woT, 4096, 4096);
  gemm_bt<0><<<dim3(32, 32), 256, 0, stream>>>(attn, woT, d_out, 4096, 4096, 4096);
}